// Round 6
// baseline (6445.348 us; speedup 1.0000x reference)
//
#include <hip/hip_runtime.h>
#include <cstdio>
#include <cstdint>

#define S8     8
#define TENC   12
#define HDIM   256
#define FDIM   316
#define BATCH  1024
#define LDEC   48
#define DBT    32
#define KA     264          // hA row stride in shorts (16B-aligned rows)
#define SCALE_ATTN 0.0625f  // 1/sqrt(256)

typedef short bf16x8 __attribute__((ext_vector_type(8)));
typedef float f32x4  __attribute__((ext_vector_type(4)));

__device__ __forceinline__ float sigf(float x) { return 1.0f / (1.0f + expf(-x)); }

__device__ __forceinline__ unsigned short f2bf(float f) {
  unsigned u = __builtin_bit_cast(unsigned, f);
  unsigned r = (u + 0x7fffu + ((u >> 16) & 1u)) >> 16;   // RNE
  return (unsigned short)r;
}
__device__ __forceinline__ float bflo(unsigned u) {
  return __builtin_bit_cast(float, u << 16);
}
__device__ __forceinline__ float bfhi(unsigned u) {
  return __builtin_bit_cast(float, u & 0xffff0000u);
}

#define MFMA(acc, a, b) acc = __builtin_amdgcn_mfma_f32_16x16x32_bf16(a, b, acc, 0, 0, 0)

// unpack 8 bf16-pairs (hi uint4 + lo uint4) -> 8 floats (hi+lo)
#define UNP8(dst, off, qh, ql) \
  dst[off+0] = bflo(qh.x)+bflo(ql.x); dst[off+1] = bfhi(qh.x)+bfhi(ql.x); \
  dst[off+2] = bflo(qh.y)+bflo(ql.y); dst[off+3] = bfhi(qh.y)+bfhi(ql.y); \
  dst[off+4] = bflo(qh.z)+bflo(ql.z); dst[off+5] = bfhi(qh.z)+bfhi(ql.z); \
  dst[off+6] = bflo(qh.w)+bflo(ql.w); dst[off+7] = bfhi(qh.w)+bfhi(ql.w);

#define DOT8(a, q, hp) \
  a = fmaf(bflo(q.x), hp[0], a); a = fmaf(bfhi(q.x), hp[1], a); \
  a = fmaf(bflo(q.y), hp[2], a); a = fmaf(bfhi(q.y), hp[3], a); \
  a = fmaf(bflo(q.z), hp[4], a); a = fmaf(bfhi(q.z), hp[5], a); \
  a = fmaf(bflo(q.w), hp[6], a); a = fmaf(bfhi(q.w), hp[7], a);

// ---------------- transpose: in [S][R][C] -> out [S][C][R] ----------------
__global__ __launch_bounds__(256) void transpose_k(const float* __restrict__ in,
                                                   float* __restrict__ out,
                                                   int R, int C) {
  __shared__ float tile[32][33];
  const int s = blockIdx.z;
  const size_t base = (size_t)s * R * C;
  const int r0 = blockIdx.y * 32, c0 = blockIdx.x * 32;
  const int tx = threadIdx.x & 31, ty = threadIdx.x >> 5;
  for (int i = ty; i < 32; i += 8) {
    int r = r0 + i, c = c0 + tx;
    if (r < R && c < C) tile[i][tx] = in[base + (size_t)r * C + c];
  }
  __syncthreads();
  for (int i = ty; i < 32; i += 8) {
    int c = c0 + i, r = r0 + tx;
    if (c < C && r < R) out[base + (size_t)c * R + r] = tile[tx][i];
  }
}

// ---- fold GEMM: out[s][r][col] = sum_e A[s][e][r] * B[s][e][col], 256x256, K=256 ----
__global__ __launch_bounds__(256) void fold_gemm(const float* __restrict__ A, size_t sA,
                                                 const float* __restrict__ Bm, size_t sB,
                                                 float* __restrict__ out, size_t sO) {
  const int s = blockIdx.y, r0 = blockIdx.x * 32, col = threadIdx.x;
  A += (size_t)s * sA; Bm += (size_t)s * sB; out += (size_t)s * sO;
  float acc[32] = {};
  for (int e = 0; e < HDIM; ++e) {
    const float bvv = Bm[(size_t)e * HDIM + col];
#pragma unroll
    for (int r = 0; r < 32; ++r) acc[r] = fmaf(A[(size_t)e * HDIM + r0 + r], bvv, acc[r]);
  }
  for (int r = 0; r < 32; ++r) out[(size_t)(r0 + r) * HDIM + col] = acc[r];
}

// ---- pack gate weights [S][1024][Ksrc] into B-fragment layout, hi+lo bf16 ----
__global__ __launch_bounds__(64) void pack_hl(const float* __restrict__ src, int Ksrc, int ksT,
                                              bf16x8* __restrict__ outhi,
                                              bf16x8* __restrict__ outlo) {
  const int s = blockIdx.z, ks = blockIdx.y, nt = blockIdx.x;
  const int lane = threadIdx.x, l15 = lane & 15, quad = lane >> 4;
  const int n = nt * 16 + l15, kb = ks * 32 + quad * 8;
  const float* row = src + ((size_t)s * 1024 + n) * Ksrc;
  union { bf16x8 v; unsigned short e[8]; } h, l;
#pragma unroll
  for (int j = 0; j < 8; ++j) {
    const int k = kb + j;
    const float v = (k < Ksrc) ? row[k] : 0.f;
    const unsigned short hi = f2bf(v);
    h.e[j] = hi;
    l.e[j] = f2bf(v - bflo(hi));
  }
  const size_t idx = (((size_t)s * ksT + ks) * 64 + nt) * 64 + lane;
  outhi[idx] = h.v;
  outlo[idx] = l.v;
}

// ---- pack attention fold matrices [S][256][256] into B-frag (single bf16) ----
__global__ __launch_bounds__(64) void pack_s(const float* __restrict__ src, int ntOff,
                                             bf16x8* __restrict__ out) {
  const int s = blockIdx.z, ks = blockIdx.y, nt = blockIdx.x;
  const int lane = threadIdx.x, l15 = lane & 15, quad = lane >> 4;
  const int n = nt * 16 + l15, kb = ks * 32 + quad * 8;
  const float* row = src + ((size_t)s * 256 + n) * 256;
  union { bf16x8 v; unsigned short e[8]; } h;
#pragma unroll
  for (int j = 0; j < 8; ++j) h.e[j] = f2bf(row[kb + j]);
  out[(((size_t)s * 8 + ks) * 32 + ntOff + nt) * 64 + lane] = h.v;
}

// ---- fold vectors: kbv = Wk^T bq ; cbias = Wo bv + b_out ----
__global__ __launch_bounds__(256) void fold_vec2(const float* __restrict__ Win,
                                                 const float* __restrict__ bin,
                                                 const float* __restrict__ Wout,
                                                 const float* __restrict__ bout,
                                                 float* __restrict__ kbv,
                                                 float* __restrict__ cbias) {
  const int s = blockIdx.x, t = threadIdx.x;
  const float* bq = bin + s * 768;
  const float* bv = bin + s * 768 + 512;
  float a0 = 0.f, a1 = 0.f;
  for (int e = 0; e < 256; ++e) {
    a0 = fmaf(Win[((size_t)s * 768 + 256 + e) * 256 + t], bq[e], a0);
    a1 = fmaf(Wout[((size_t)s * 256 + t) * 256 + e], bv[e], a1);
  }
  kbv[s * 256 + t] = a0;
  cbias[s * 256 + t] = a1 + bout[s * 256 + t];
}

__global__ void fold_bias(const float* __restrict__ a, const float* __restrict__ b,
                          float* __restrict__ o, int n) {
  int i = blockIdx.x * 256 + threadIdx.x;
  if (i < n) o[i] = a[i] + b[i];
}

__global__ void build_decin(const float* __restrict__ x, const float* __restrict__ tgt,
                            float* __restrict__ dec_in) {
  int idx = blockIdx.x * 256 + threadIdx.x;
  if (idx >= LDEC * BATCH) return;
  int l = idx >> 10, b = idx & 1023;
  dec_in[idx] = (l == 0) ? x[(size_t)b * 96 * FDIM + 95 * FDIM]
                         : tgt[(size_t)b * LDEC + (l - 1)];
}

// =============== persistent MFMA encoder + decoder-LSTM (phase A) ===============
// grid 256 x 512thr. s = bid&7 (XCD weight locality), 32 batch rows/block.
// Decoder attention is NOT here: h_dec does not depend on it. Each decoder
// step only runs the LSTM and streams h_l (bf16) to hd for phase B.
__global__ __launch_bounds__(512, 2) void enc_dec(
    const float* __restrict__ x,
    const bf16x8* __restrict__ WxH, const bf16x8* __restrict__ WxL,
    const bf16x8* __restrict__ WeH, const bf16x8* __restrict__ WeL,
    const bf16x8* __restrict__ WdH, const bf16x8* __restrict__ WdL,
    const bf16x8* __restrict__ AMvF,
    const float* __restrict__ be, const float* __restrict__ bd,
    const float* __restrict__ wihd,
    const float* __restrict__ kbv,
    const float* __restrict__ decin,
    unsigned short* __restrict__ kp, unsigned short* __restrict__ vp,
    float* __restrict__ kbsg,          // [T][S][B]
    unsigned short* __restrict__ hd)   // [L][S][B][256] bf16
{
  __shared__ unsigned short hAhi[DBT * KA];
  __shared__ unsigned short hAlo[DBT * KA];
  __shared__ float red[DBT][16];
  __shared__ float kbs[TENC][DBT];

  const int bid = blockIdx.x;
  const int s = bid & 7, b0 = (bid >> 3) * DBT;
  const int tid = threadIdx.x;
  const int w = tid >> 6, lane = tid & 63, l15 = lane & 15, quad = lane >> 4;

  for (int i = tid; i < DBT * KA; i += 512) { hAhi[i] = 0; hAlo[i] = 0; }

  float beV[4][2], bdV[4][2], wdV[4][2];
#pragma unroll
  for (int c = 0; c < 4; ++c)
#pragma unroll
    for (int st = 0; st < 2; ++st) {
      const int J = c * 256 + 32 * w + 16 * st + l15;
      beV[c][st] = be[s * 1024 + J];
      bdV[c][st] = bd[s * 1024 + J];
      wdV[c][st] = wihd[s * 1024 + J];
    }
  float cst[2][2][4];
#pragma unroll
  for (int a = 0; a < 2; ++a)
#pragma unroll
    for (int b = 0; b < 2; ++b)
#pragma unroll
      for (int r = 0; r < 4; ++r) cst[a][b][r] = 0.f;

  const bf16x8* wxh = WxH + (size_t)s * 10 * 64 * 64;
  const bf16x8* wxl = WxL + (size_t)s * 10 * 64 * 64;
  const bf16x8* weh = WeH + (size_t)s * 8 * 64 * 64;
  const bf16x8* wel = WeL + (size_t)s * 8 * 64 * 64;
  const bf16x8* wdh = WdH + (size_t)s * 8 * 64 * 64;
  const bf16x8* wdl = WdL + (size_t)s * 8 * 64 * 64;
  const bf16x8* amv = AMvF + (size_t)s * 8 * 32 * 64;
  const float* kvv = kbv + s * 256;

  __syncthreads();

  // ===================== encoder =====================
  for (int t = 0; t < TENC; ++t) {
    f32x4 acc[2][2][4];
#pragma unroll
    for (int mt = 0; mt < 2; ++mt)
#pragma unroll
      for (int st = 0; st < 2; ++st)
#pragma unroll
        for (int c = 0; c < 4; ++c) acc[mt][st][c] = (f32x4){0.f, 0.f, 0.f, 0.f};

    const size_t xoff = (size_t)(s * TENC + t) * FDIM;
    for (int ks = 0; ks < 10; ++ks) {
      bf16x8 axh[2], axl[2];
#pragma unroll
      for (int mt = 0; mt < 2; ++mt) {
        const float* xr = x + (size_t)(b0 + 16 * mt + l15) * (96 * FDIM) + xoff + ks * 32 + quad * 8;
        const float4 v0 = *(const float4*)xr;
        float4 v1;
        if (ks == 9 && quad == 3) v1 = make_float4(0.f, 0.f, 0.f, 0.f);
        else v1 = *(const float4*)(xr + 4);
        const float vv[8] = {v0.x, v0.y, v0.z, v0.w, v1.x, v1.y, v1.z, v1.w};
        union { bf16x8 v; unsigned short e[8]; } uh, ul;
#pragma unroll
        for (int j = 0; j < 8; ++j) {
          const unsigned short hi = f2bf(vv[j]);
          uh.e[j] = hi;
          ul.e[j] = f2bf(vv[j] - bflo(hi));
        }
        axh[mt] = uh.v; axl[mt] = ul.v;
      }
#pragma unroll
      for (int st = 0; st < 2; ++st)
#pragma unroll
        for (int c = 0; c < 4; ++c) {
          const int nt = c * 16 + 2 * w + st;
          const bf16x8 bh = wxh[(ks * 64 + nt) * 64 + lane];
          const bf16x8 bl = wxl[(ks * 64 + nt) * 64 + lane];
          MFMA(acc[0][st][c], axh[0], bh); MFMA(acc[0][st][c], axh[0], bl); MFMA(acc[0][st][c], axl[0], bh);
          MFMA(acc[1][st][c], axh[1], bh); MFMA(acc[1][st][c], axh[1], bl); MFMA(acc[1][st][c], axl[1], bh);
        }
    }
    for (int ks = 0; ks < 8; ++ks) {
      bf16x8 ah[2], al[2];
#pragma unroll
      for (int mt = 0; mt < 2; ++mt) {
        const int ao = (16 * mt + l15) * KA + ks * 32 + quad * 8;
        ah[mt] = *(const bf16x8*)&hAhi[ao];
        al[mt] = *(const bf16x8*)&hAlo[ao];
      }
#pragma unroll
      for (int st = 0; st < 2; ++st)
#pragma unroll
        for (int c = 0; c < 4; ++c) {
          const int nt = c * 16 + 2 * w + st;
          const bf16x8 bh = weh[(ks * 64 + nt) * 64 + lane];
          const bf16x8 bl = wel[(ks * 64 + nt) * 64 + lane];
          MFMA(acc[0][st][c], ah[0], bh); MFMA(acc[0][st][c], ah[0], bl); MFMA(acc[0][st][c], al[0], bh);
          MFMA(acc[1][st][c], ah[1], bh); MFMA(acc[1][st][c], ah[1], bl); MFMA(acc[1][st][c], al[1], bh);
        }
    }
    float hv[2][2][4];
#pragma unroll
    for (int mt = 0; mt < 2; ++mt)
#pragma unroll
      for (int st = 0; st < 2; ++st)
#pragma unroll
        for (int reg = 0; reg < 4; ++reg) {
          const float gi = sigf(acc[mt][st][0][reg] + beV[0][st]);
          const float gf = sigf(acc[mt][st][1][reg] + beV[1][st]);
          const float gg = tanhf(acc[mt][st][2][reg] + beV[2][st]);
          const float go = sigf(acc[mt][st][3][reg] + beV[3][st]);
          const float cn = fmaf(gf, cst[mt][st][reg], gi * gg);
          cst[mt][st][reg] = cn;
          hv[mt][st][reg] = go * tanhf(cn);
        }
    __syncthreads();
#pragma unroll
    for (int mt = 0; mt < 2; ++mt)
#pragma unroll
      for (int st = 0; st < 2; ++st)
#pragma unroll
        for (int reg = 0; reg < 4; ++reg) {
          const int R = 16 * mt + 4 * quad + reg;
          const int J = 32 * w + 16 * st + l15;
          const float v = hv[mt][st][reg];
          const unsigned short hi = f2bf(v);
          hAhi[R * KA + J] = hi;
          hAlo[R * KA + J] = f2bf(v - bflo(hi));
        }
    __syncthreads();

    // kp/vp projection MFMA: A = new h (hi/lo), B = AMvF (single bf16)
    f32x4 ak[2][2][2];
#pragma unroll
    for (int mt = 0; mt < 2; ++mt)
#pragma unroll
      for (int st = 0; st < 2; ++st)
#pragma unroll
        for (int kv = 0; kv < 2; ++kv) ak[mt][st][kv] = (f32x4){0.f, 0.f, 0.f, 0.f};
    for (int ks = 0; ks < 8; ++ks) {
      bf16x8 ah[2], al[2];
#pragma unroll
      for (int mt = 0; mt < 2; ++mt) {
        const int ao = (16 * mt + l15) * KA + ks * 32 + quad * 8;
        ah[mt] = *(const bf16x8*)&hAhi[ao];
        al[mt] = *(const bf16x8*)&hAlo[ao];
      }
#pragma unroll
      for (int st = 0; st < 2; ++st)
#pragma unroll
        for (int kv = 0; kv < 2; ++kv) {
          const int nt = kv * 16 + 2 * w + st;
          const bf16x8 b = amv[(ks * 32 + nt) * 64 + lane];
          MFMA(ak[0][st][kv], ah[0], b); MFMA(ak[0][st][kv], al[0], b);
          MFMA(ak[1][st][kv], ah[1], b); MFMA(ak[1][st][kv], al[1], b);
        }
    }
    {
      unsigned short* kpw = kp + (((size_t)t * S8 + s) * BATCH + b0) * HDIM;
      unsigned short* vpw = vp + (((size_t)t * S8 + s) * BATCH + b0) * HDIM;
#pragma unroll
      for (int mt = 0; mt < 2; ++mt)
#pragma unroll
        for (int st = 0; st < 2; ++st)
#pragma unroll
          for (int reg = 0; reg < 4; ++reg) {
            const int R = 16 * mt + 4 * quad + reg;
            const int J2 = 32 * w + 16 * st + l15;
            kpw[(size_t)R * HDIM + J2] = f2bf(ak[mt][st][0][reg]);
            vpw[(size_t)R * HDIM + J2] = f2bf(ak[mt][st][1][reg]);
          }
    }
    // kb = kbv . h_new
    {
      const int bbk = tid >> 4, p = tid & 15;
      const uint4 qh0 = *(const uint4*)&hAhi[bbk * KA + p * 16];
      const uint4 qh1 = *(const uint4*)&hAhi[bbk * KA + p * 16 + 8];
      const uint4 ql0 = *(const uint4*)&hAlo[bbk * KA + p * 16];
      const uint4 ql1 = *(const uint4*)&hAlo[bbk * KA + p * 16 + 8];
      float hh[16];
      UNP8(hh, 0, qh0, ql0);
      UNP8(hh, 8, qh1, ql1);
      float a = 0.f;
#pragma unroll
      for (int q = 0; q < 16; ++q) a = fmaf(kvv[p * 16 + q], hh[q], a);
      red[bbk][p] = a;
    }
    __syncthreads();
    if (tid < DBT) {
      float a = 0.f;
#pragma unroll
      for (int p = 0; p < 16; ++p) a += red[tid][p];
      kbs[t][tid] = a;
    }
    __syncthreads();
  }

  // write kbs to global for phase B
  for (int i = tid; i < TENC * DBT; i += 512) {
    const int t = i >> 5, b = i & 31;
    kbsg[((size_t)t * S8 + s) * BATCH + b0 + b] = kbs[t][b];
  }

  // ===================== decoder LSTM only (phase A) =====================
  for (int l = 0; l < LDEC; ++l) {
    f32x4 acc[2][2][4];
#pragma unroll
    for (int mt = 0; mt < 2; ++mt)
#pragma unroll
      for (int st = 0; st < 2; ++st)
#pragma unroll
        for (int c = 0; c < 4; ++c) acc[mt][st][c] = (f32x4){0.f, 0.f, 0.f, 0.f};

    for (int ks = 0; ks < 8; ++ks) {
      bf16x8 ah[2], al[2];
#pragma unroll
      for (int mt = 0; mt < 2; ++mt) {
        const int ao = (16 * mt + l15) * KA + ks * 32 + quad * 8;
        ah[mt] = *(const bf16x8*)&hAhi[ao];
        al[mt] = *(const bf16x8*)&hAlo[ao];
      }
#pragma unroll
      for (int st = 0; st < 2; ++st)
#pragma unroll
        for (int c = 0; c < 4; ++c) {
          const int nt = c * 16 + 2 * w + st;
          const bf16x8 bh = wdh[(ks * 64 + nt) * 64 + lane];
          const bf16x8 bl = wdl[(ks * 64 + nt) * 64 + lane];
          MFMA(acc[0][st][c], ah[0], bh); MFMA(acc[0][st][c], ah[0], bl); MFMA(acc[0][st][c], al[0], bh);
          MFMA(acc[1][st][c], ah[1], bh); MFMA(acc[1][st][c], ah[1], bl); MFMA(acc[1][st][c], al[1], bh);
        }
    }
    float hv[2][2][4];
#pragma unroll
    for (int mt = 0; mt < 2; ++mt)
#pragma unroll
      for (int reg = 0; reg < 4; ++reg) {
        const int R = 16 * mt + 4 * quad + reg;
        const float it = decin[(size_t)l * BATCH + b0 + R];
#pragma unroll
        for (int st = 0; st < 2; ++st) {
          const float gi = sigf(fmaf(it, wdV[0][st], acc[mt][st][0][reg] + bdV[0][st]));
          const float gf = sigf(fmaf(it, wdV[1][st], acc[mt][st][1][reg] + bdV[1][st]));
          const float gg = tanhf(fmaf(it, wdV[2][st], acc[mt][st][2][reg] + bdV[2][st]));
          const float go = sigf(fmaf(it, wdV[3][st], acc[mt][st][3][reg] + bdV[3][st]));
          const float cn = fmaf(gf, cst[mt][st][reg], gi * gg);
          cst[mt][st][reg] = cn;
          hv[mt][st][reg] = go * tanhf(cn);
        }
      }
    __syncthreads();
    {
      unsigned short* hdw = hd + (((size_t)l * S8 + s) * BATCH + b0) * HDIM;
#pragma unroll
      for (int mt = 0; mt < 2; ++mt)
#pragma unroll
        for (int st = 0; st < 2; ++st)
#pragma unroll
          for (int reg = 0; reg < 4; ++reg) {
            const int R = 16 * mt + 4 * quad + reg;
            const int J = 32 * w + 16 * st + l15;
            const float v = hv[mt][st][reg];
            const unsigned short hi = f2bf(v);
            hAhi[R * KA + J] = hi;
            hAlo[R * KA + J] = f2bf(v - bflo(hi));
            hdw[(size_t)R * HDIM + J] = hi;
          }
    }
    __syncthreads();
  }
}

// =============== phase B: attention + out_fc, embarrassingly parallel ===============
// grid (256, 4) x 512thr: block = (s = x&7, btile = x>>3, l-chunk of 12 = y).
// kp/vp/hd each read once; per-l reuse comes from L2-resident block slices.
__global__ __launch_bounds__(512, 2) void attn_fc(
    const unsigned short* __restrict__ kp, const unsigned short* __restrict__ vp,
    const unsigned short* __restrict__ hd, const float* __restrict__ kbsg,
    const float* __restrict__ cbias, const float* __restrict__ Wfo,
    const float* __restrict__ bfo, float* __restrict__ douts)
{
  __shared__ float hs[DBT][257];
  __shared__ float redS[DBT][TENC][9];
  __shared__ float sc[DBT][TENC];
  __shared__ float red[DBT][16];
  __shared__ float kbsL[TENC][DBT];

  const int sb = blockIdx.x, s = sb & 7, b0 = (sb >> 3) * DBT;
  const int tid = threadIdx.x;
  for (int i = tid; i < TENC * DBT; i += 512) {
    const int t = i >> 5, b = i & 31;
    kbsL[t][b] = kbsg[((size_t)t * S8 + s) * BATCH + b0 + b];
  }
  const float* cbs = cbias + s * 256;
  const float* wfo = Wfo + s * 512;
  const float bfos = bfo[s];
  const int l0 = blockIdx.y * 12;

  for (int li = 0; li < 12; ++li) {
    const int l = l0 + li;
    __syncthreads();
    // stage hd tile (32 rows x 256) bf16 -> fp32 LDS
    for (int i = tid; i < DBT * 32; i += 512) {
      const int row = i >> 5, c = i & 31;
      const uint4 q = *(const uint4*)(hd + (((size_t)l * S8 + s) * BATCH + b0 + row) * HDIM + c * 8);
      float* dst = &hs[row][c * 8];
      dst[0] = bflo(q.x); dst[1] = bfhi(q.x);
      dst[2] = bflo(q.y); dst[3] = bfhi(q.y);
      dst[4] = bflo(q.z); dst[5] = bfhi(q.z);
      dst[6] = bflo(q.w); dst[7] = bfhi(q.w);
    }
    __syncthreads();
    // scores: (32 b) x (8 k-chunks of 32)
    if (tid < 256) {
      const int bbs = tid & 31, p = tid >> 5;
      const int k0 = p * 32;
      float hh[32];
#pragma unroll
      for (int j = 0; j < 32; ++j) hh[j] = hs[bbs][k0 + j];
#pragma unroll 2
      for (int tts = 0; tts < TENC; ++tts) {
        const uint4* kq = (const uint4*)(kp + (((size_t)tts * S8 + s) * BATCH + b0 + bbs) * HDIM + k0);
        float a = 0.f;
#pragma unroll
        for (int g = 0; g < 4; ++g) {
          const uint4 q = kq[g];
          const float* hp = &hh[g * 8];
          DOT8(a, q, hp);
        }
        redS[bbs][tts][p] = a;
      }
    }
    __syncthreads();
    if (tid < 384) {
      const int bbs = tid & 31, tts = tid >> 5;
      float a = kbsL[tts][bbs];
#pragma unroll
      for (int q = 0; q < 8; ++q) a += redS[bbs][tts][q];
      sc[bbs][tts] = a * SCALE_ATTN;
    }
    __syncthreads();
    if (tid < DBT) {
      float m = sc[tid][0];
#pragma unroll
      for (int t2 = 1; t2 < TENC; ++t2) m = fmaxf(m, sc[tid][t2]);
      float e[TENC], sum = 0.f;
#pragma unroll
      for (int t2 = 0; t2 < TENC; ++t2) { e[t2] = expf(sc[tid][t2] - m); sum += e[t2]; }
      const float inv = 1.0f / sum;
#pragma unroll
      for (int t2 = 0; t2 < TENC; ++t2) sc[tid][t2] = e[t2] * inv;
    }
    __syncthreads();
    // ctx + out_fc
    {
      const int bbc = tid >> 4, p = tid & 15, e0 = p * 16;
      float ctxv[16];
#pragma unroll
      for (int ei = 0; ei < 16; ++ei) ctxv[ei] = cbs[e0 + ei];
      for (int tt = 0; tt < TENC; ++tt) {
        const float a = sc[bbc][tt];
        const uint4* vpr = (const uint4*)(vp + (((size_t)tt * S8 + s) * BATCH + b0 + bbc) * HDIM + e0);
#pragma unroll
        for (int hf = 0; hf < 2; ++hf) {
          const uint4 q = vpr[hf];
          const int e = hf * 8;
          ctxv[e]     = fmaf(a, bflo(q.x), ctxv[e]);
          ctxv[e + 1] = fmaf(a, bfhi(q.x), ctxv[e + 1]);
          ctxv[e + 2] = fmaf(a, bflo(q.y), ctxv[e + 2]);
          ctxv[e + 3] = fmaf(a, bfhi(q.y), ctxv[e + 3]);
          ctxv[e + 4] = fmaf(a, bflo(q.z), ctxv[e + 4]);
          ctxv[e + 5] = fmaf(a, bfhi(q.z), ctxv[e + 5]);
          ctxv[e + 6] = fmaf(a, bflo(q.w), ctxv[e + 6]);
          ctxv[e + 7] = fmaf(a, bfhi(q.w), ctxv[e + 7]);
        }
      }
      float part = 0.f;
#pragma unroll
      for (int ei = 0; ei < 16; ++ei) part = fmaf(ctxv[ei], wfo[256 + e0 + ei], part);
#pragma unroll
      for (int ki = 0; ki < 16; ++ki) part = fmaf(hs[bbc][e0 + ki], wfo[e0 + ki], part);
      red[bbc][p] = part;
    }
    __syncthreads();
    if (tid < DBT) {
      float a = 0.f;
#pragma unroll
      for (int p = 0; p < 16; ++p) a += red[tid][p];
      douts[((size_t)l * S8 + s) * BATCH + b0 + tid] = a + bfos;
    }
  }
}

// ---------------- final fc over streams ----------------
__global__ void final_fc(const float* __restrict__ douts, const float* __restrict__ Wfc,
                         const float* __restrict__ bfc, float* __restrict__ out) {
  int idx = blockIdx.x * 256 + threadIdx.x;
  if (idx >= BATCH * LDEC) return;
  int b = idx / LDEC, l = idx - b * LDEC;
  float a = bfc[0];
#pragma unroll
  for (int s = 0; s < S8; ++s)
    a = fmaf(douts[((size_t)l * S8 + s) * BATCH + b], Wfc[s], a);
  out[idx] = a;
}

extern "C" void kernel_launch(void* const* d_in, const int* in_sizes, int n_in,
                              void* d_out, int out_size, void* d_ws, size_t ws_size,
                              hipStream_t stream) {
  const float* x          = (const float*)d_in[0];
  const float* tgt        = (const float*)d_in[1];
  const float* W_ih_e     = (const float*)d_in[2];
  const float* W_hh_e     = (const float*)d_in[3];
  const float* b_ih_e     = (const float*)d_in[4];
  const float* b_hh_e     = (const float*)d_in[5];
  const float* W_ih_d     = (const float*)d_in[6];
  const float* W_hh_d     = (const float*)d_in[7];
  const float* b_ih_d     = (const float*)d_in[8];
  const float* b_hh_d     = (const float*)d_in[9];
  const float* W_in_attn  = (const float*)d_in[10];
  const float* b_in_attn  = (const float*)d_in[11];
  const float* W_out_attn = (const float*)d_in[12];
  const float* b_out_attn = (const float*)d_in[13];
  const float* W_fcout    = (const float*)d_in[14];
  const float* b_fcout    = (const float*)d_in[15];
  const float* W_fc       = (const float*)d_in[16];
  const float* b_fc       = (const float*)d_in[17];

  char* wsb = (char*)d_ws;
  size_t off = 0;
  auto alloc = [&](size_t bytes) {
    void* p = wsb + off; off += (bytes + 255) & ~(size_t)255; return p;
  };
  unsigned short* kp = (unsigned short*)alloc((size_t)TENC * S8 * BATCH * HDIM * 2);
  unsigned short* vp = (unsigned short*)alloc((size_t)TENC * S8 * BATCH * HDIM * 2);
  unsigned short* hd = (unsigned short*)alloc((size_t)LDEC * S8 * BATCH * HDIM * 2);
  float*  douts = (float*)alloc((size_t)LDEC * S8 * BATCH * 4);
  float*  decin = (float*)alloc((size_t)LDEC * BATCH * 4);
  float*  kbsg  = (float*)alloc((size_t)TENC * S8 * BATCH * 4);
  bf16x8* WxH   = (bf16x8*)alloc((size_t)S8 * 10 * 64 * 64 * 16);
  bf16x8* WxL   = (bf16x8*)alloc((size_t)S8 * 10 * 64 * 64 * 16);
  bf16x8* WeH   = (bf16x8*)alloc((size_t)S8 * 8 * 64 * 64 * 16);
  bf16x8* WeL   = (bf16x8*)alloc((size_t)S8 * 8 * 64 * 64 * 16);
  bf16x8* WdH   = (bf16x8*)alloc((size_t)S8 * 8 * 64 * 64 * 16);
  bf16x8* WdL   = (bf16x8*)alloc((size_t)S8 * 8 * 64 * 64 * 16);
  bf16x8* AMvF  = (bf16x8*)alloc((size_t)S8 * 8 * 32 * 64 * 16);
  float*  kbv   = (float*)alloc((size_t)S8 * 256 * 4);
  float*  cbias = (float*)alloc((size_t)S8 * 256 * 4);
  float*  beF   = (float*)alloc((size_t)S8 * 1024 * 4);
  float*  bdF   = (float*)alloc((size_t)S8 * 1024 * 4);
  if (off > ws_size) {
    fprintf(stderr, "kernel_launch: ws too small: need %zu bytes, have %zu\n", off, ws_size);
    return;
  }
  // prep temporaries aliased into hd (hd is written only by enc_dec, after
  // these are consumed; same stream serializes)
  float* Pmat  = (float*)hd;
  float* Mvmat = (float*)hd + (size_t)S8 * 256 * 256;
  float* WoT   = (float*)hd + (size_t)2 * S8 * 256 * 256;

  // ---- one-time weight preparation ----
  transpose_k<<<dim3(8, 8, S8), 256, 0, stream>>>(W_out_attn, WoT, 256, 256);
  fold_gemm<<<dim3(8, S8), 256, 0, stream>>>(W_in_attn, (size_t)768 * 256,
                                             W_in_attn + 256 * 256, (size_t)768 * 256,
                                             Pmat, (size_t)256 * 256);
  fold_gemm<<<dim3(8, S8), 256, 0, stream>>>(WoT, (size_t)256 * 256,
                                             W_in_attn + 2 * 256 * 256, (size_t)768 * 256,
                                             Mvmat, (size_t)256 * 256);
  pack_hl<<<dim3(64, 10, S8), 64, 0, stream>>>(W_ih_e, FDIM, 10, WxH, WxL);
  pack_hl<<<dim3(64, 8, S8), 64, 0, stream>>>(W_hh_e, 256, 8, WeH, WeL);
  pack_hl<<<dim3(64, 8, S8), 64, 0, stream>>>(W_hh_d, 256, 8, WdH, WdL);
  pack_s<<<dim3(16, 8, S8), 64, 0, stream>>>(Pmat, 0, AMvF);
  pack_s<<<dim3(16, 8, S8), 64, 0, stream>>>(Mvmat, 16, AMvF);
  fold_vec2<<<S8, 256, 0, stream>>>(W_in_attn, b_in_attn, W_out_attn, b_out_attn, kbv, cbias);
  fold_bias<<<(S8 * 1024 + 255) / 256, 256, 0, stream>>>(b_ih_e, b_hh_e, beF, S8 * 1024);
  fold_bias<<<(S8 * 1024 + 255) / 256, 256, 0, stream>>>(b_ih_d, b_hh_d, bdF, S8 * 1024);
  build_decin<<<(LDEC * BATCH + 255) / 256, 256, 0, stream>>>(x, tgt, decin);

  // phase A: recurrence (encoder + decoder LSTM)
  enc_dec<<<256, 512, 0, stream>>>(
      x, WxH, WxL, WeH, WeL, WdH, WdL, AMvF, beF, bdF, W_ih_d,
      kbv, decin, kp, vp, kbsg, hd);

  // phase B: attention + out_fc (parallel over l)
  attn_fc<<<dim3(256, 4), 512, 0, stream>>>(kp, vp, hd, kbsg, cbias,
                                            W_fcout, b_fcout, douts);

  final_fc<<<(BATCH * LDEC + 255) / 256, 256, 0, stream>>>(douts, W_fc, b_fc, (float*)d_out);
}